// Round 16
// baseline (1530.768 us; speedup 1.0000x reference)
//
#include <hip/hip_runtime.h>
#include <hip/hip_bf16.h>
#include <math.h>

#define DM   1024
#define DF   4096
#define NH   8
#define NB   4
#define NS   2048
#define MT   (NB*NS)   // 8192 tokens
#define MQ   2048      // M-split quarter (hp = 134 MB -> L3-resident; R14 proved nq=2 loses this)
#define KC   4096      // gemm2 K-split chunk
#define NKS  8         // gemm2 K-splits

typedef __bf16 bf16;
typedef __bf16 bf16x4 __attribute__((ext_vector_type(4)));
typedef __bf16 bf16x8 __attribute__((ext_vector_type(8)));
typedef float  f32x4  __attribute__((ext_vector_type(4)));
typedef float  f32x16 __attribute__((ext_vector_type(16)));

typedef __attribute__((address_space(3))) unsigned int u32_lds;
typedef const __attribute__((address_space(1))) void cv_glob;

__device__ __forceinline__ void gload16(const void* g, const void* l) {
    __builtin_amdgcn_global_load_lds(
        (cv_glob*)(unsigned long long)g,
        (u32_lds*)(unsigned int)(unsigned long long)l,
        16, 0, 0);
}

// tanh-form GELU: |gelu_tanh - gelu_erf| <= ~2e-3 absolute; 3x cheaper than erff.
__device__ __forceinline__ float gelu_f(float x) {
    float u = -1.5957691216057308f * fmaf(0.044715f * x, x * x, x);
    return x * __builtin_amdgcn_rcpf(1.f + __expf(u));
}

// SWIZZLE CONVENTION (T2, both-sides): every bf16 buffer consumed by GEMM staging is
// stored with 16B chunks permuted within each 128B (64-elem) row-block:
// elem e of row r stored at e ^ ((r&7)<<3). gload_lds copies linearly; ds_read
// XORs byte ^ ((row&7)<<4). Proven R2-R15: SQ_LDS_BANK_CONFLICT == 0.

// ---------------- x f32 -> bf16 (swizzled rows = tokens) ----------------
__global__ __launch_bounds__(256) void k_cvtx(const float* __restrict__ in, bf16* __restrict__ out) {
    long i = ((long)blockIdx.x * 256 + threadIdx.x) * 8;
    float4 a = *(const float4*)(in + i);
    float4 b = *(const float4*)(in + i + 4);
    bf16x8 o;
    o[0]=(bf16)a.x; o[1]=(bf16)a.y; o[2]=(bf16)a.z; o[3]=(bf16)a.w;
    o[4]=(bf16)b.x; o[5]=(bf16)b.y; o[6]=(bf16)b.z; o[7]=(bf16)b.w;
    long t7 = (i >> 10) & 7;
    *(bf16x8*)(out + (i ^ (t7 << 3))) = o;
}

// ---- transpose+convert+swizzle, 64x64 tile: out[c][r ^ ((c&7)<<3)] = (bf16)in[r*C+c] ----
__global__ __launch_bounds__(256) void k_tcvt2(const float* __restrict__ in, bf16* __restrict__ out,
                                               int C, long outStride, long inBatch, long outBatch) {
    __shared__ float t[64][65];
    const float* ip = in + (long)blockIdx.z * inBatch;
    bf16* op = out + (long)blockIdx.z * outBatch;
    const int c0 = blockIdx.x * 64, r0 = blockIdx.y * 64;
    const int tid = threadIdx.x;
    const int rr = tid >> 4, cc = tid & 15;
    #pragma unroll
    for (int it = 0; it < 4; ++it) {
        const int r = rr + 16 * it;
        float4 v = *(const float4*)(ip + (long)(r0 + r) * C + c0 + cc * 4);
        t[r][cc*4+0] = v.x; t[r][cc*4+1] = v.y; t[r][cc*4+2] = v.z; t[r][cc*4+3] = v.w;
    }
    __syncthreads();
    #pragma unroll
    for (int it = 0; it < 2; ++it) {
        const int oc = (tid >> 3) + 32 * it;
        const int e0 = (tid & 7) * 8;
        bf16 tmp[8];
        #pragma unroll
        for (int j = 0; j < 8; ++j) tmp[j] = (bf16)t[e0 + j][oc];
        const int rs = e0 ^ ((oc & 7) << 3);
        *(bf16x8*)(op + (long)(c0 + oc) * outStride + r0 + rs) = *(bf16x8*)tmp;
    }
}

// ---------------- state projection: sp[b][d] = rs[b]@Ws[:,d] + bs[d] ----------------
__global__ __launch_bounds__(256) void k_sproj2(const float* __restrict__ rs, const float* __restrict__ Ws,
                                                const float* __restrict__ bs, float* __restrict__ sp) {
    const int d0 = blockIdx.x * 16;
    const int ks = threadIdx.x >> 4, dd = threadIdx.x & 15;
    const float* r = rs + blockIdx.y * DM;
    float acc = 0.f;
    #pragma unroll 4
    for (int k = ks * 64; k < ks * 64 + 64; ++k)
        acc += r[k] * Ws[(long)k * DM + d0 + dd];
    __shared__ float red[256];
    red[threadIdx.x] = acc;
    __syncthreads();
    if (threadIdx.x < 16) {
        float v = bs[d0 + threadIdx.x];
        #pragma unroll
        for (int s = 0; s < 16; ++s) v += red[threadIdx.x + 16 * s];
        sp[blockIdx.y * DM + d0 + threadIdx.x] = v;
    }
}

// ---------------- gate: logits = g@Wg + bg; softmax -> wout [t][8] ----------------
__global__ __launch_bounds__(256) void k_gate(const bf16* __restrict__ g, const float* __restrict__ Wg,
                                              const float* __restrict__ bg, float* __restrict__ wout) {
    int lane = threadIdx.x & 63, wid = threadIdx.x >> 6;
    long t = (long)blockIdx.x * 4 + wid;
    const bf16* gr = g + t * DM + lane * 16;
    bf16x8 v0 = *(const bf16x8*)gr;
    bf16x8 v1 = *(const bf16x8*)(gr + 8);
    float s0=0,s1=0,s2=0,s3=0,s4=0,s5=0,s6=0,s7=0;
    #pragma unroll
    for (int i = 0; i < 16; ++i) {
        float gv = (float)((i < 8) ? v0[i] : v1[i - 8]);
        const float4* wr = (const float4*)(Wg + (long)(lane * 16 + i) * NH);
        float4 wa = wr[0], wb = wr[1];
        s0 += gv*wa.x; s1 += gv*wa.y; s2 += gv*wa.z; s3 += gv*wa.w;
        s4 += gv*wb.x; s5 += gv*wb.y; s6 += gv*wb.z; s7 += gv*wb.w;
    }
    #pragma unroll
    for (int off = 32; off >= 1; off >>= 1) {
        s0 += __shfl_xor(s0, off); s1 += __shfl_xor(s1, off);
        s2 += __shfl_xor(s2, off); s3 += __shfl_xor(s3, off);
        s4 += __shfl_xor(s4, off); s5 += __shfl_xor(s5, off);
        s6 += __shfl_xor(s6, off); s7 += __shfl_xor(s7, off);
    }
    float l0=s0+bg[0], l1=s1+bg[1], l2=s2+bg[2], l3=s3+bg[3];
    float l4=s4+bg[4], l5=s5+bg[5], l6=s6+bg[6], l7=s7+bg[7];
    float m = fmaxf(fmaxf(fmaxf(l0,l1),fmaxf(l2,l3)), fmaxf(fmaxf(l4,l5),fmaxf(l6,l7)));
    float e0=expf(l0-m), e1=expf(l1-m), e2=expf(l2-m), e3=expf(l3-m);
    float e4=expf(l4-m), e5=expf(l5-m), e6=expf(l6-m), e7=expf(l7-m);
    float inv = 1.f / (e0+e1+e2+e3+e4+e5+e6+e7);
    if (lane == 0) {
        float* wo = wout + t * NH;
        wo[0]=e0*inv; wo[1]=e1*inv; wo[2]=e2*inv; wo[3]=e3*inv;
        wo[4]=e4*inv; wo[5]=e5*inv; wo[6]=e6*inv; wo[7]=e7*inv;
    }
}

// ============ 256x256x64 bf16 GEMM — R15 structure, 32x32x16 MFMA ============
// R9/R13/R15 loop skeleton FROZEN (staging, vmcnt(2), 1 barrier/tile, MAPs, swizzle).
// ONLY change vs R15: MFMA shape 16x16x32 -> 32x32x16 (m119: 2495 TF vs 2075 ->
// per-tile MFMA demand 2484 -> 2051 cy/CU, and per-wave MFMA instruction count halves
// 32 -> 16). DS reads unchanged: 16 b128/wave/tile.
// Fragment layouts (mirror of the verified 16x16 mapping):
//   A: row = lane&31, k = 8*(lane>>5)+i   (one bf16x8 = 16B per fragment)
//   B (from Bt rows): col = lane&31, same k pattern
//   C/D: col = lane&31, row = (reg&3) + 8*(reg>>2) + 4*(lane>>5)   [m74/m101]
// Wave out 64x64 = 2x2 fragments of 32x32; acc = f32x16[2][2] (64 regs).
// MAP 1 (gemm1): per round of 256 ids, XCD x (=id&7) works a contiguous 4bx x 8by rectangle.
// MAP 2 (gemm2): bz = id&7 -> one K-chunk per XCD; bx,by sweep within.
// EPI 0: gelu(acc+bias[col]+sp[t>>11][col])        -> bf16 outH (unswizzled)
// EPI 1: w[t][col>>12]*gelu(acc+bias[col])         -> bf16 outH (swizzled)
// EPI 2: bz==0: acc+sum_h w*b2 -> outF (f32) ; bz>0: acc -> parts[bz-1] (bf16)
template<int EPI, int MAP>
__global__ __launch_bounds__(1024, 4) void k_g2(
    const bf16* __restrict__ A, long lda,
    const bf16* __restrict__ Bt, long ldb,
    int K, long kcs, int gm, int gn,
    bf16* __restrict__ outH, float* __restrict__ outF, long ldc,
    const float* __restrict__ bias,
    const float* __restrict__ aux1, const float* __restrict__ aux2,
    bf16* __restrict__ parts, long pStride)
{
    __shared__ __align__(16) unsigned char lsA[3][32 * 1024];
    __shared__ __align__(16) unsigned char lsB[2][32 * 1024];
    const int tid = threadIdx.x, lane = tid & 63, wid = tid >> 6;

    const int id = blockIdx.x;
    int bx, by, bz;
    if (MAP == 1) {            // grid 1024 = 8bx x 128by, rounds of 256
        const int x = id & 7, j = (id >> 3) & 31, r = id >> 8;
        bx = (x & 1) * 4 + (j & 3);
        by = (x >> 1) * 8 + (j >> 2) + r * 32;
        bz = 0;
    } else if (MAP == 2) {     // grid 256 = 8bx x 4by x 8bz
        bz = id & 7;
        bx = (id >> 3) & 7;
        by = id >> 6;
    } else {
        bx = id % gm; by = (id / gm) % gn; bz = id / (gm * gn);
    }
    const long tileM = (long)bx * 256;
    const long tileN = (long)by * 256;
    const bf16* Ab = A + tileM * lda + (long)bz * kcs;
    const bf16* Bb = Bt + tileN * ldb + (long)bz * kcs;

    const int wr = wid >> 2, wc = wid & 3;      // 4 x 4 waves, wave out 64x64
    const int l31 = lane & 31, kh5 = lane >> 5;
    const int swz = (lane & 7) << 4;

    f32x16 acc[2][2];
    #pragma unroll
    for (int mi = 0; mi < 2; ++mi)
        #pragma unroll
        for (int ni = 0; ni < 2; ++ni)
            #pragma unroll
            for (int e = 0; e < 16; ++e) acc[mi][ni][e] = 0.f;

    auto STAGE_A = [&](int t) {
        const int buf = t % 3; const long kO = (long)t * 64;
        #pragma unroll
        for (int is = 0; is < 2; ++is) {
            const int o = is * 16384 + tid * 16;
            gload16(Ab + (long)(o >> 7) * lda + kO + ((o & 127) >> 1), lsA[buf] + o);
        }
    };
    auto STAGE_B = [&](int t) {
        const int buf = t & 1; const long kO = (long)t * 64;
        #pragma unroll
        for (int is = 0; is < 2; ++is) {
            const int o = is * 16384 + tid * 16;
            gload16(Bb + (long)(o >> 7) * ldb + kO + ((o & 127) >> 1), lsB[buf] + o);
        }
    };

    const int NT = K >> 6;                      // >= 16 at all call sites
    STAGE_A(0); STAGE_B(0); STAGE_A(1);
    asm volatile("s_waitcnt vmcnt(2)" ::: "memory");
    __builtin_amdgcn_s_barrier();
    for (int t = 0; t < NT; ++t) {
        const unsigned char* As = lsA[t % 3];
        const unsigned char* Bs = lsB[t & 1];
        if (t + 1 < NT) STAGE_B(t + 1);
        if (t + 2 < NT) STAGE_A(t + 2);
        #pragma unroll
        for (int kh = 0; kh < 2; ++kh) {        // each kh covers 2 k-steps of 16 (32 k)
            bf16x8 av[2][2], bv[2][2];          // [kstep][frag]
            #pragma unroll
            for (int ks = 0; ks < 2; ++ks) {
                const int kb = (((kh * 2 + ks) * 32) + kh5 * 16) ^ swz;
                #pragma unroll
                for (int mi = 0; mi < 2; ++mi)
                    av[ks][mi] = *(const bf16x8*)(As + ((wr * 64 + mi * 32 + l31) << 7) + kb);
                #pragma unroll
                for (int ni = 0; ni < 2; ++ni)
                    bv[ks][ni] = *(const bf16x8*)(Bs + ((wc * 64 + ni * 32 + l31) << 7) + kb);
            }
            __builtin_amdgcn_s_setprio(1);
            #pragma unroll
            for (int ks = 0; ks < 2; ++ks)
                #pragma unroll
                for (int mi = 0; mi < 2; ++mi)
                    #pragma unroll
                    for (int ni = 0; ni < 2; ++ni)
                        acc[mi][ni] = __builtin_amdgcn_mfma_f32_32x32x16_bf16(
                            av[ks][mi], bv[ks][ni], acc[mi][ni], 0, 0, 0);
            __builtin_amdgcn_s_setprio(0);
        }
        if (t + 2 < NT) {
            asm volatile("s_waitcnt vmcnt(2)" ::: "memory");
        } else {
            asm volatile("s_waitcnt vmcnt(0)" ::: "memory");
        }
        __builtin_amdgcn_s_barrier();
    }

    // epilogue: 32x32 C/D layout col = lane&31, row = (reg&3) + 8*(reg>>2) + 4*(lane>>5)
    const long rowBase = tileM + wr * 64;
    const int  colBase = (int)tileN + wc * 64;
    #pragma unroll
    for (int mi = 0; mi < 2; ++mi) {
        #pragma unroll
        for (int ni = 0; ni < 2; ++ni) {
            const int col = colBase + ni * 32 + l31;
            #pragma unroll
            for (int gq = 0; gq < 4; ++gq) {
                #pragma unroll
                for (int j = 0; j < 4; ++j) {
                    const long tk = rowBase + mi * 32 + j + gq * 8 + kh5 * 4;
                    float v = acc[mi][ni][gq * 4 + j];
                    if constexpr (EPI == 0) {
                        v += bias[col] + aux1[(long)(tk >> 11) * DM + col];
                        v = gelu_f(v);
                        outH[tk * ldc + col] = (bf16)v;
                    } else if constexpr (EPI == 1) {
                        v += bias[col];
                        v = gelu_f(v);
                        v *= aux1[tk * NH + (col >> 12)];
                        outH[tk * ldc + (col ^ (((int)tk & 7) << 3))] = (bf16)v;
                    } else {
                        if (bz == 0) {
                            float bsum = 0.f;
                            #pragma unroll
                            for (int hh = 0; hh < NH; ++hh)
                                bsum += aux1[tk * NH + hh] * aux2[(long)hh * DM + col];
                            outF[tk * ldc + col] = v + bsum;
                        } else {
                            parts[(long)(bz - 1) * pStride + tk * ldc + col] = (bf16)v;
                        }
                    }
                }
            }
        }
    }
}

// ---------------- reduce: out += sum of bf16 partials (8 elems/thread) ----------------
__global__ __launch_bounds__(256) void k_red(float* __restrict__ out, const bf16* __restrict__ parts,
                                             long pStride) {
    long i = ((long)blockIdx.x * 256 + threadIdx.x) * 8;
    float4 v0 = *(float4*)(out + i);
    float4 v1 = *(float4*)(out + i + 4);
    #pragma unroll
    for (int p = 0; p < NKS - 1; ++p) {
        bf16x8 q = *(const bf16x8*)(parts + (long)p * pStride + i);
        v0.x += (float)q[0]; v0.y += (float)q[1]; v0.z += (float)q[2]; v0.w += (float)q[3];
        v1.x += (float)q[4]; v1.y += (float)q[5]; v1.z += (float)q[6]; v1.w += (float)q[7];
    }
    *(float4*)(out + i) = v0;
    *(float4*)(out + i + 4) = v1;
}

extern "C" void kernel_launch(void* const* d_in, const int* in_sizes, int n_in,
                              void* d_out, int out_size, void* d_ws, size_t ws_size,
                              hipStream_t stream)
{
    const float* x  = (const float*)d_in[0];
    const float* rs = (const float*)d_in[1];
    const float* W1 = (const float*)d_in[2];
    const float* b1 = (const float*)d_in[3];
    const float* W2 = (const float*)d_in[4];
    const float* b2 = (const float*)d_in[5];
    const float* Ws = (const float*)d_in[6];
    const float* bs = (const float*)d_in[7];
    const float* Wi = (const float*)d_in[8];
    const float* bi = (const float*)d_in[9];
    const float* Wg = (const float*)d_in[10];
    const float* bg = (const float*)d_in[11];

    float* out  = (float*)d_out;                    // [8192][1024] f32
    float* wout = out + (size_t)MT * DM;            // [8192][8]   f32 (output 1)

    unsigned char* ws = (unsigned char*)d_ws;
    size_t ofs = 0;
    auto alloc = [&](size_t bytes) { void* p = ws + ofs; ofs += (bytes + 255) & ~(size_t)255; return p; };

    bf16*  xbf  = (bf16*)alloc((size_t)MT * DM * 2);          // 16.8 MB (swizzled)
    bf16*  WiT  = (bf16*)alloc((size_t)DM * DM * 2);          //  2.1 MB (swizzled)
    bf16*  g    = (bf16*)alloc((size_t)MT * DM * 2);          // 16.8 MB (linear)
    float* sp   = (float*)alloc((size_t)NB * DM * 4);         // 16 KB
    bf16*  W1T  = (bf16*)alloc((size_t)NH * DF * DM * 2);     // 67.1 MB [hf][d] swizzled
    bf16*  W2T  = (bf16*)alloc((size_t)NH * DF * DM * 2);     // 67.1 MB [d][hf] swizzled
    bf16*  hp   = (bf16*)alloc((size_t)MQ * NH * DF * 2);     // 134.2 MB (swizzled, L3-resident)
    bf16*  part = (bf16*)alloc((size_t)(NKS - 1) * MQ * DM * 2);   // 29.4 MB (bf16)
    const long pStride = (long)MQ * DM;

    // stage 0: conversions / transposes / projections
    k_cvtx<<<(MT * DM) / (256 * 8), 256, 0, stream>>>(x, xbf);
    k_tcvt2<<<dim3(DM / 64, DM / 64, 1), 256, 0, stream>>>(Wi, WiT, DM, DM, 0, 0);
    k_sproj2<<<dim3(DM / 16, NB), 256, 0, stream>>>(rs, Ws, bs, sp);

    // stage 1: input proj -> gelu(combined) -> g, then gate weights
    k_g2<0, 0><<<(MT / 256) * (DM / 256), 1024, 0, stream>>>(
        xbf, DM, WiT, DM, DM, 0, MT / 256, DM / 256,
        g, nullptr, DM, bi, sp, nullptr, nullptr, 0);
    k_gate<<<MT / 4, 256, 0, stream>>>(g, Wg, bg, wout);

    // weight transposes
    k_tcvt2<<<dim3(DF / 64, DM / 64, NH), 256, 0, stream>>>(
        W1, W1T, DF, DM, (long)DM * DF, (long)DF * DM);
    k_tcvt2<<<dim3(DM / 64, DF / 64, NH), 256, 0, stream>>>(
        W2, W2T, DM, (long)NH * DF, (long)DF * DM, DF);

    // stage 2: per M-quarter: gemm1 (all heads) -> hp ; gemm2 (K-split 8) ; reduce
    for (int q = 0; q < MT / MQ; ++q) {
        const bf16*  xq = xbf + (size_t)q * MQ * DM;
        const float* wq = wout + (size_t)q * MQ * NH;
        float*       oq = out + (size_t)q * MQ * DM;
        k_g2<1, 1><<<(MQ / 256) * (NH * DF / 256), 1024, 0, stream>>>(
            xq, DM, W1T, DM, DM, 0, MQ / 256, NH * DF / 256,
            hp, nullptr, (long)NH * DF, b1, wq, nullptr, nullptr, 0);
        k_g2<2, 2><<<(MQ / 256) * (DM / 256) * NKS, 1024, 0, stream>>>(
            hp, (long)NH * DF, W2T, (long)NH * DF, KC, KC, MQ / 256, DM / 256,
            nullptr, oq, DM, nullptr, wq, b2, part, pStride);
        k_red<<<(MQ * DM) / (256 * 8), 256, 0, stream>>>(oq, part, pStride);
    }
    (void)in_sizes; (void)n_in; (void)out_size;
}

// Round 17
// 1368.235 us; speedup vs baseline: 1.1188x; 1.1188x over previous
//
#include <hip/hip_runtime.h>
#include <hip/hip_bf16.h>
#include <math.h>

#define DM   1024
#define DF   4096
#define NH   8
#define NB   4
#define NS   2048
#define MT   (NB*NS)   // 8192 tokens
#define MQ   2048      // M-split quarter (hp = 134 MB -> L3-resident; R14 proved nq=2 loses this)
#define KC   4096      // gemm2 K-split chunk
#define NKS  8         // gemm2 K-splits

typedef __bf16 bf16;
typedef __bf16 bf16x4 __attribute__((ext_vector_type(4)));
typedef __bf16 bf16x8 __attribute__((ext_vector_type(8)));
typedef float  f32x4  __attribute__((ext_vector_type(4)));

typedef __attribute__((address_space(3))) unsigned int u32_lds;
typedef const __attribute__((address_space(1))) void cv_glob;

__device__ __forceinline__ void gload16(const void* g, const void* l) {
    __builtin_amdgcn_global_load_lds(
        (cv_glob*)(unsigned long long)g,
        (u32_lds*)(unsigned int)(unsigned long long)l,
        16, 0, 0);
}

// tanh-form GELU: |gelu_tanh - gelu_erf| <= ~2e-3 absolute; 3x cheaper than erff.
__device__ __forceinline__ float gelu_f(float x) {
    float u = -1.5957691216057308f * fmaf(0.044715f * x, x * x, x);
    return x * __builtin_amdgcn_rcpf(1.f + __expf(u));
}

// SWIZZLE CONVENTION (T2, both-sides): every bf16 buffer consumed by GEMM staging is
// stored with 16B chunks permuted within each 128B (64-elem) row-block:
// elem e of row r stored at e ^ ((r&7)<<3). gload_lds copies linearly; ds_read
// XORs byte ^ ((row&7)<<4). Proven R2-R15: SQ_LDS_BANK_CONFLICT == 0 with 16x16 fragments.
// R16 lesson: 32x32 fragments (rows lane&31, single column) force a 4-way conflict under
// this swizzle (1.678e7 conflicts, +15% time) -> 16x16x32 MFMA is the right shape here.

// ---------------- x f32 -> bf16 (swizzled rows = tokens) ----------------
__global__ __launch_bounds__(256) void k_cvtx(const float* __restrict__ in, bf16* __restrict__ out) {
    long i = ((long)blockIdx.x * 256 + threadIdx.x) * 8;
    float4 a = *(const float4*)(in + i);
    float4 b = *(const float4*)(in + i + 4);
    bf16x8 o;
    o[0]=(bf16)a.x; o[1]=(bf16)a.y; o[2]=(bf16)a.z; o[3]=(bf16)a.w;
    o[4]=(bf16)b.x; o[5]=(bf16)b.y; o[6]=(bf16)b.z; o[7]=(bf16)b.w;
    long t7 = (i >> 10) & 7;
    *(bf16x8*)(out + (i ^ (t7 << 3))) = o;
}

// ---- transpose+convert+swizzle, 64x64 tile: out[c][r ^ ((c&7)<<3)] = (bf16)in[r*C+c] ----
__global__ __launch_bounds__(256) void k_tcvt2(const float* __restrict__ in, bf16* __restrict__ out,
                                               int C, long outStride, long inBatch, long outBatch) {
    __shared__ float t[64][65];
    const float* ip = in + (long)blockIdx.z * inBatch;
    bf16* op = out + (long)blockIdx.z * outBatch;
    const int c0 = blockIdx.x * 64, r0 = blockIdx.y * 64;
    const int tid = threadIdx.x;
    const int rr = tid >> 4, cc = tid & 15;
    #pragma unroll
    for (int it = 0; it < 4; ++it) {
        const int r = rr + 16 * it;
        float4 v = *(const float4*)(ip + (long)(r0 + r) * C + c0 + cc * 4);
        t[r][cc*4+0] = v.x; t[r][cc*4+1] = v.y; t[r][cc*4+2] = v.z; t[r][cc*4+3] = v.w;
    }
    __syncthreads();
    #pragma unroll
    for (int it = 0; it < 2; ++it) {
        const int oc = (tid >> 3) + 32 * it;
        const int e0 = (tid & 7) * 8;
        bf16 tmp[8];
        #pragma unroll
        for (int j = 0; j < 8; ++j) tmp[j] = (bf16)t[e0 + j][oc];
        const int rs = e0 ^ ((oc & 7) << 3);
        *(bf16x8*)(op + (long)(c0 + oc) * outStride + r0 + rs) = *(bf16x8*)tmp;
    }
}

// ---------------- state projection: sp[b][d] = rs[b]@Ws[:,d] + bs[d] ----------------
__global__ __launch_bounds__(256) void k_sproj2(const float* __restrict__ rs, const float* __restrict__ Ws,
                                                const float* __restrict__ bs, float* __restrict__ sp) {
    const int d0 = blockIdx.x * 16;
    const int ks = threadIdx.x >> 4, dd = threadIdx.x & 15;
    const float* r = rs + blockIdx.y * DM;
    float acc = 0.f;
    #pragma unroll 4
    for (int k = ks * 64; k < ks * 64 + 64; ++k)
        acc += r[k] * Ws[(long)k * DM + d0 + dd];
    __shared__ float red[256];
    red[threadIdx.x] = acc;
    __syncthreads();
    if (threadIdx.x < 16) {
        float v = bs[d0 + threadIdx.x];
        #pragma unroll
        for (int s = 0; s < 16; ++s) v += red[threadIdx.x + 16 * s];
        sp[blockIdx.y * DM + d0 + threadIdx.x] = v;
    }
}

// ---------------- gate: logits = g@Wg + bg; softmax -> wout [t][8] ----------------
__global__ __launch_bounds__(256) void k_gate(const bf16* __restrict__ g, const float* __restrict__ Wg,
                                              const float* __restrict__ bg, float* __restrict__ wout) {
    int lane = threadIdx.x & 63, wid = threadIdx.x >> 6;
    long t = (long)blockIdx.x * 4 + wid;
    const bf16* gr = g + t * DM + lane * 16;
    bf16x8 v0 = *(const bf16x8*)gr;
    bf16x8 v1 = *(const bf16x8*)(gr + 8);
    float s0=0,s1=0,s2=0,s3=0,s4=0,s5=0,s6=0,s7=0;
    #pragma unroll
    for (int i = 0; i < 16; ++i) {
        float gv = (float)((i < 8) ? v0[i] : v1[i - 8]);
        const float4* wr = (const float4*)(Wg + (long)(lane * 16 + i) * NH);
        float4 wa = wr[0], wb = wr[1];
        s0 += gv*wa.x; s1 += gv*wa.y; s2 += gv*wa.z; s3 += gv*wa.w;
        s4 += gv*wb.x; s5 += gv*wb.y; s6 += gv*wb.z; s7 += gv*wb.w;
    }
    #pragma unroll
    for (int off = 32; off >= 1; off >>= 1) {
        s0 += __shfl_xor(s0, off); s1 += __shfl_xor(s1, off);
        s2 += __shfl_xor(s2, off); s3 += __shfl_xor(s3, off);
        s4 += __shfl_xor(s4, off); s5 += __shfl_xor(s5, off);
        s6 += __shfl_xor(s6, off); s7 += __shfl_xor(s7, off);
    }
    float l0=s0+bg[0], l1=s1+bg[1], l2=s2+bg[2], l3=s3+bg[3];
    float l4=s4+bg[4], l5=s5+bg[5], l6=s6+bg[6], l7=s7+bg[7];
    float m = fmaxf(fmaxf(fmaxf(l0,l1),fmaxf(l2,l3)), fmaxf(fmaxf(l4,l5),fmaxf(l6,l7)));
    float e0=expf(l0-m), e1=expf(l1-m), e2=expf(l2-m), e3=expf(l3-m);
    float e4=expf(l4-m), e5=expf(l5-m), e6=expf(l6-m), e7=expf(l7-m);
    float inv = 1.f / (e0+e1+e2+e3+e4+e5+e6+e7);
    if (lane == 0) {
        float* wo = wout + t * NH;
        wo[0]=e0*inv; wo[1]=e1*inv; wo[2]=e2*inv; wo[3]=e3*inv;
        wo[4]=e4*inv; wo[5]=e5*inv; wo[6]=e6*inv; wo[7]=e7*inv;
    }
}

// ============ 256x256x64 bf16 GEMM — 16 waves (4/SIMD), occupancy-driven overlap ============
// R15 FINAL (measured best: 1370.7 us total, ~810 TF/dispatch). K-loop FROZEN (R11 pre-commit;
// explicit schedules R8/R10/R11/R12 regressed; 32x32 MFMA R16 regressed via bank conflicts).
// 16 waves as 4M x 4N, wave out 64x64, acc[4][4] f32x4; __launch_bounds__(1024,4) ->
// VGPR<=128, 4 waves/SIMD resident: read/MFMA bursts of different waves co-schedule on the
// separate LDS/matrix pipes (m114 overlap).
// LDS: A 3-deep x 32K + B 2-deep x 32K = 160 KB. Stages at tile top (B(t+1), A(t+2));
// boundary s_waitcnt vmcnt(2) keeps A(t+2) in flight; single barrier/tile bounds skew.
// MAP 1 (gemm1): per round of 256 ids, XCD x (=id&7) works a contiguous 4bx x 8by rectangle.
// MAP 2 (gemm2): bz = id&7 -> one K-chunk per XCD; bx,by sweep within.
// EPI 0: gelu(acc+bias[col]+sp[t>>11][col])        -> bf16 outH (unswizzled)
// EPI 1: w[t][col>>12]*gelu(acc+bias[col])         -> bf16 outH (swizzled)
// EPI 2: bz==0: acc+sum_h w*b2 -> outF (f32) ; bz>0: acc -> parts[bz-1] (bf16, safe per R14)
template<int EPI, int MAP>
__global__ __launch_bounds__(1024, 4) void k_g2(
    const bf16* __restrict__ A, long lda,
    const bf16* __restrict__ Bt, long ldb,
    int K, long kcs, int gm, int gn,
    bf16* __restrict__ outH, float* __restrict__ outF, long ldc,
    const float* __restrict__ bias,
    const float* __restrict__ aux1, const float* __restrict__ aux2,
    bf16* __restrict__ parts, long pStride)
{
    __shared__ __align__(16) unsigned char lsA[3][32 * 1024];
    __shared__ __align__(16) unsigned char lsB[2][32 * 1024];
    const int tid = threadIdx.x, lane = tid & 63, wid = tid >> 6;

    const int id = blockIdx.x;
    int bx, by, bz;
    if (MAP == 1) {            // grid 1024 = 8bx x 128by, rounds of 256
        const int x = id & 7, j = (id >> 3) & 31, r = id >> 8;
        bx = (x & 1) * 4 + (j & 3);
        by = (x >> 1) * 8 + (j >> 2) + r * 32;
        bz = 0;
    } else if (MAP == 2) {     // grid 256 = 8bx x 4by x 8bz
        bz = id & 7;
        bx = (id >> 3) & 7;
        by = id >> 6;
    } else {
        bx = id % gm; by = (id / gm) % gn; bz = id / (gm * gn);
    }
    const long tileM = (long)bx * 256;
    const long tileN = (long)by * 256;
    const bf16* Ab = A + tileM * lda + (long)bz * kcs;
    const bf16* Bb = Bt + tileN * ldb + (long)bz * kcs;

    const int wr = wid >> 2, wc = wid & 3;      // 4 x 4 waves, wave out 64x64
    const int l15 = lane & 15, kd = lane >> 4;
    const int swz = (lane & 7) << 4;

    f32x4 acc[4][4];
    #pragma unroll
    for (int m = 0; m < 4; ++m)
        #pragma unroll
        for (int n = 0; n < 4; ++n) { f32x4 z = {0.f,0.f,0.f,0.f}; acc[m][n] = z; }

    auto STAGE_A = [&](int t) {
        const int buf = t % 3; const long kO = (long)t * 64;
        #pragma unroll
        for (int is = 0; is < 2; ++is) {
            const int o = is * 16384 + tid * 16;
            gload16(Ab + (long)(o >> 7) * lda + kO + ((o & 127) >> 1), lsA[buf] + o);
        }
    };
    auto STAGE_B = [&](int t) {
        const int buf = t & 1; const long kO = (long)t * 64;
        #pragma unroll
        for (int is = 0; is < 2; ++is) {
            const int o = is * 16384 + tid * 16;
            gload16(Bb + (long)(o >> 7) * ldb + kO + ((o & 127) >> 1), lsB[buf] + o);
        }
    };

    const int NT = K >> 6;                      // >= 16 at all call sites
    STAGE_A(0); STAGE_B(0); STAGE_A(1);
    asm volatile("s_waitcnt vmcnt(2)" ::: "memory");
    __builtin_amdgcn_s_barrier();
    for (int t = 0; t < NT; ++t) {
        const unsigned char* As = lsA[t % 3];
        const unsigned char* Bs = lsB[t & 1];
        if (t + 1 < NT) STAGE_B(t + 1);
        if (t + 2 < NT) STAGE_A(t + 2);
        #pragma unroll
        for (int kk = 0; kk < 2; ++kk) {
            const int kb = (kk * 64 + kd * 16) ^ swz;
            bf16x8 av[4], bv[4];
            #pragma unroll
            for (int m = 0; m < 4; ++m)
                av[m] = *(const bf16x8*)(As + ((wr * 64 + m * 16 + l15) << 7) + kb);
            #pragma unroll
            for (int n = 0; n < 4; ++n)
                bv[n] = *(const bf16x8*)(Bs + ((wc * 64 + n * 16 + l15) << 7) + kb);
            __builtin_amdgcn_s_setprio(1);
            #pragma unroll
            for (int m = 0; m < 4; ++m)
                #pragma unroll
                for (int n = 0; n < 4; ++n)
                    acc[m][n] = __builtin_amdgcn_mfma_f32_16x16x32_bf16(av[m], bv[n], acc[m][n], 0, 0, 0);
            __builtin_amdgcn_s_setprio(0);
        }
        if (t + 2 < NT) {
            asm volatile("s_waitcnt vmcnt(2)" ::: "memory");
        } else {
            asm volatile("s_waitcnt vmcnt(0)" ::: "memory");
        }
        __builtin_amdgcn_s_barrier();
    }

    // epilogue: C/D layout col = lane&15, row = (lane>>4)*4 + j
    const long rowBase = tileM + wr * 64;
    const int  colBase = (int)tileN + wc * 64;
    #pragma unroll
    for (int m = 0; m < 4; ++m) {
        const long r0 = rowBase + m * 16 + (kd * 4);
        #pragma unroll
        for (int n = 0; n < 4; ++n) {
            const int col = colBase + n * 16 + l15;
            #pragma unroll
            for (int j = 0; j < 4; ++j) {
                const long tk = r0 + j;
                float v = acc[m][n][j];
                if constexpr (EPI == 0) {
                    v += bias[col] + aux1[(long)(tk >> 11) * DM + col];
                    v = gelu_f(v);
                    outH[tk * ldc + col] = (bf16)v;
                } else if constexpr (EPI == 1) {
                    v += bias[col];
                    v = gelu_f(v);
                    v *= aux1[tk * NH + (col >> 12)];
                    outH[tk * ldc + (col ^ (((int)tk & 7) << 3))] = (bf16)v;
                } else {
                    if (bz == 0) {
                        float bsum = 0.f;
                        #pragma unroll
                        for (int hh = 0; hh < NH; ++hh)
                            bsum += aux1[tk * NH + hh] * aux2[(long)hh * DM + col];
                        outF[tk * ldc + col] = v + bsum;
                    } else {
                        parts[(long)(bz - 1) * pStride + tk * ldc + col] = (bf16)v;
                    }
                }
            }
        }
    }
}

// ---------------- reduce: out += sum of bf16 partials (8 elems/thread) ----------------
__global__ __launch_bounds__(256) void k_red(float* __restrict__ out, const bf16* __restrict__ parts,
                                             long pStride) {
    long i = ((long)blockIdx.x * 256 + threadIdx.x) * 8;
    float4 v0 = *(float4*)(out + i);
    float4 v1 = *(float4*)(out + i + 4);
    #pragma unroll
    for (int p = 0; p < NKS - 1; ++p) {
        bf16x8 q = *(const bf16x8*)(parts + (long)p * pStride + i);
        v0.x += (float)q[0]; v0.y += (float)q[1]; v0.z += (float)q[2]; v0.w += (float)q[3];
        v1.x += (float)q[4]; v1.y += (float)q[5]; v1.z += (float)q[6]; v1.w += (float)q[7];
    }
    *(float4*)(out + i) = v0;
    *(float4*)(out + i + 4) = v1;
}

extern "C" void kernel_launch(void* const* d_in, const int* in_sizes, int n_in,
                              void* d_out, int out_size, void* d_ws, size_t ws_size,
                              hipStream_t stream)
{
    const float* x  = (const float*)d_in[0];
    const float* rs = (const float*)d_in[1];
    const float* W1 = (const float*)d_in[2];
    const float* b1 = (const float*)d_in[3];
    const float* W2 = (const float*)d_in[4];
    const float* b2 = (const float*)d_in[5];
    const float* Ws = (const float*)d_in[6];
    const float* bs = (const float*)d_in[7];
    const float* Wi = (const float*)d_in[8];
    const float* bi = (const float*)d_in[9];
    const float* Wg = (const float*)d_in[10];
    const float* bg = (const float*)d_in[11];

    float* out  = (float*)d_out;                    // [8192][1024] f32
    float* wout = out + (size_t)MT * DM;            // [8192][8]   f32 (output 1)

    unsigned char* ws = (unsigned char*)d_ws;
    size_t ofs = 0;
    auto alloc = [&](size_t bytes) { void* p = ws + ofs; ofs += (bytes + 255) & ~(size_t)255; return p; };

    bf16*  xbf  = (bf16*)alloc((size_t)MT * DM * 2);          // 16.8 MB (swizzled)
    bf16*  WiT  = (bf16*)alloc((size_t)DM * DM * 2);          //  2.1 MB (swizzled)
    bf16*  g    = (bf16*)alloc((size_t)MT * DM * 2);          // 16.8 MB (linear)
    float* sp   = (float*)alloc((size_t)NB * DM * 4);         // 16 KB
    bf16*  W1T  = (bf16*)alloc((size_t)NH * DF * DM * 2);     // 67.1 MB [hf][d] swizzled
    bf16*  W2T  = (bf16*)alloc((size_t)NH * DF * DM * 2);     // 67.1 MB [d][hf] swizzled
    bf16*  hp   = (bf16*)alloc((size_t)MQ * NH * DF * 2);     // 134.2 MB (swizzled, L3-resident)
    bf16*  part = (bf16*)alloc((size_t)(NKS - 1) * MQ * DM * 2);   // 29.4 MB (bf16)
    const long pStride = (long)MQ * DM;

    // stage 0: conversions / transposes / projections
    k_cvtx<<<(MT * DM) / (256 * 8), 256, 0, stream>>>(x, xbf);
    k_tcvt2<<<dim3(DM / 64, DM / 64, 1), 256, 0, stream>>>(Wi, WiT, DM, DM, 0, 0);
    k_sproj2<<<dim3(DM / 16, NB), 256, 0, stream>>>(rs, Ws, bs, sp);

    // stage 1: input proj -> gelu(combined) -> g, then gate weights
    k_g2<0, 0><<<(MT / 256) * (DM / 256), 1024, 0, stream>>>(
        xbf, DM, WiT, DM, DM, 0, MT / 256, DM / 256,
        g, nullptr, DM, bi, sp, nullptr, nullptr, 0);
    k_gate<<<MT / 4, 256, 0, stream>>>(g, Wg, bg, wout);

    // weight transposes
    k_tcvt2<<<dim3(DF / 64, DM / 64, NH), 256, 0, stream>>>(
        W1, W1T, DF, DM, (long)DM * DF, (long)DF * DM);
    k_tcvt2<<<dim3(DM / 64, DF / 64, NH), 256, 0, stream>>>(
        W2, W2T, DM, (long)NH * DF, (long)DF * DM, DF);

    // stage 2: per M-quarter: gemm1 (all heads) -> hp ; gemm2 (K-split 8) ; reduce
    for (int q = 0; q < MT / MQ; ++q) {
        const bf16*  xq = xbf + (size_t)q * MQ * DM;
        const float* wq = wout + (size_t)q * MQ * NH;
        float*       oq = out + (size_t)q * MQ * DM;
        k_g2<1, 1><<<(MQ / 256) * (NH * DF / 256), 1024, 0, stream>>>(
            xq, DM, W1T, DM, DM, 0, MQ / 256, NH * DF / 256,
            hp, nullptr, (long)NH * DF, b1, wq, nullptr, nullptr, 0);
        k_g2<2, 2><<<(MQ / 256) * (DM / 256) * NKS, 1024, 0, stream>>>(
            hp, (long)NH * DF, W2T, (long)NH * DF, KC, KC, MQ / 256, DM / 256,
            nullptr, oq, DM, nullptr, wq, b2, part, pStride);
        k_red<<<(MQ * DM) / (256 * 8), 256, 0, stream>>>(oq, part, pStride);
    }
    (void)in_sizes; (void)n_in; (void)out_size;
}

// Round 18
// 1355.981 us; speedup vs baseline: 1.1289x; 1.0090x over previous
//
#include <hip/hip_runtime.h>
#include <hip/hip_bf16.h>
#include <math.h>

#define DM   1024
#define DF   4096
#define NH   8
#define NB   4
#define NS   2048
#define MT   (NB*NS)   // 8192 tokens
#define MQ   2048      // M-split quarter (hp = 134 MB -> L3-resident; R14 proved nq=2 loses this)
#define KC   4096      // gemm2 K-split chunk
#define NKS  8         // gemm2 K-splits

typedef __bf16 bf16;
typedef __bf16 bf16x4 __attribute__((ext_vector_type(4)));
typedef __bf16 bf16x8 __attribute__((ext_vector_type(8)));
typedef float  f32x4  __attribute__((ext_vector_type(4)));

typedef __attribute__((address_space(3))) unsigned int u32_lds;
typedef const __attribute__((address_space(1))) void cv_glob;

__device__ __forceinline__ void gload16(const void* g, const void* l) {
    __builtin_amdgcn_global_load_lds(
        (cv_glob*)(unsigned long long)g,
        (u32_lds*)(unsigned int)(unsigned long long)l,
        16, 0, 0);
}

// tanh-form GELU: |gelu_tanh - gelu_erf| <= ~2e-3 absolute; 3x cheaper than erff.
__device__ __forceinline__ float gelu_f(float x) {
    float u = -1.5957691216057308f * fmaf(0.044715f * x, x * x, x);
    return x * __builtin_amdgcn_rcpf(1.f + __expf(u));
}

// SWIZZLE CONVENTION (T2, both-sides): every bf16 buffer consumed by GEMM staging is
// stored with 16B chunks permuted within each 128B (64-elem) row-block:
// elem e of row r stored at e ^ ((r&7)<<3). gload_lds copies linearly; ds_read
// XORs byte ^ ((row&7)<<4). Proven R2-R17: SQ_LDS_BANK_CONFLICT == 0 with 16x16 fragments.
// (R16: 32x32 fragments force 4-way conflicts under this swizzle -> 16x16x32 is final.)

// ---------------- x f32 -> bf16 (swizzled rows = tokens) ----------------
__global__ __launch_bounds__(256) void k_cvtx(const float* __restrict__ in, bf16* __restrict__ out) {
    long i = ((long)blockIdx.x * 256 + threadIdx.x) * 8;
    float4 a = *(const float4*)(in + i);
    float4 b = *(const float4*)(in + i + 4);
    bf16x8 o;
    o[0]=(bf16)a.x; o[1]=(bf16)a.y; o[2]=(bf16)a.z; o[3]=(bf16)a.w;
    o[4]=(bf16)b.x; o[5]=(bf16)b.y; o[6]=(bf16)b.z; o[7]=(bf16)b.w;
    long t7 = (i >> 10) & 7;
    *(bf16x8*)(out + (i ^ (t7 << 3))) = o;
}

// ---- transpose+convert+swizzle, 64x64 tile: out[c][r ^ ((c&7)<<3)] = (bf16)in[r*C+c] ----
__global__ __launch_bounds__(256) void k_tcvt2(const float* __restrict__ in, bf16* __restrict__ out,
                                               int C, long outStride, long inBatch, long outBatch) {
    __shared__ float t[64][65];
    const float* ip = in + (long)blockIdx.z * inBatch;
    bf16* op = out + (long)blockIdx.z * outBatch;
    const int c0 = blockIdx.x * 64, r0 = blockIdx.y * 64;
    const int tid = threadIdx.x;
    const int rr = tid >> 4, cc = tid & 15;
    #pragma unroll
    for (int it = 0; it < 4; ++it) {
        const int r = rr + 16 * it;
        float4 v = *(const float4*)(ip + (long)(r0 + r) * C + c0 + cc * 4);
        t[r][cc*4+0] = v.x; t[r][cc*4+1] = v.y; t[r][cc*4+2] = v.z; t[r][cc*4+3] = v.w;
    }
    __syncthreads();
    #pragma unroll
    for (int it = 0; it < 2; ++it) {
        const int oc = (tid >> 3) + 32 * it;
        const int e0 = (tid & 7) * 8;
        bf16 tmp[8];
        #pragma unroll
        for (int j = 0; j < 8; ++j) tmp[j] = (bf16)t[e0 + j][oc];
        const int rs = e0 ^ ((oc & 7) << 3);
        *(bf16x8*)(op + (long)(c0 + oc) * outStride + r0 + rs) = *(bf16x8*)tmp;
    }
}

// ---------------- state projection: sp[b][d] = rs[b]@Ws[:,d] + bs[d] ----------------
__global__ __launch_bounds__(256) void k_sproj2(const float* __restrict__ rs, const float* __restrict__ Ws,
                                                const float* __restrict__ bs, float* __restrict__ sp) {
    const int d0 = blockIdx.x * 16;
    const int ks = threadIdx.x >> 4, dd = threadIdx.x & 15;
    const float* r = rs + blockIdx.y * DM;
    float acc = 0.f;
    #pragma unroll 4
    for (int k = ks * 64; k < ks * 64 + 64; ++k)
        acc += r[k] * Ws[(long)k * DM + d0 + dd];
    __shared__ float red[256];
    red[threadIdx.x] = acc;
    __syncthreads();
    if (threadIdx.x < 16) {
        float v = bs[d0 + threadIdx.x];
        #pragma unroll
        for (int s = 0; s < 16; ++s) v += red[threadIdx.x + 16 * s];
        sp[blockIdx.y * DM + d0 + threadIdx.x] = v;
    }
}

// ---------------- gate: logits = g@Wg + bg; softmax -> wout [t][8] ----------------
__global__ __launch_bounds__(256) void k_gate(const bf16* __restrict__ g, const float* __restrict__ Wg,
                                              const float* __restrict__ bg, float* __restrict__ wout) {
    int lane = threadIdx.x & 63, wid = threadIdx.x >> 6;
    long t = (long)blockIdx.x * 4 + wid;
    const bf16* gr = g + t * DM + lane * 16;
    bf16x8 v0 = *(const bf16x8*)gr;
    bf16x8 v1 = *(const bf16x8*)(gr + 8);
    float s0=0,s1=0,s2=0,s3=0,s4=0,s5=0,s6=0,s7=0;
    #pragma unroll
    for (int i = 0; i < 16; ++i) {
        float gv = (float)((i < 8) ? v0[i] : v1[i - 8]);
        const float4* wr = (const float4*)(Wg + (long)(lane * 16 + i) * NH);
        float4 wa = wr[0], wb = wr[1];
        s0 += gv*wa.x; s1 += gv*wa.y; s2 += gv*wa.z; s3 += gv*wa.w;
        s4 += gv*wb.x; s5 += gv*wb.y; s6 += gv*wb.z; s7 += gv*wb.w;
    }
    #pragma unroll
    for (int off = 32; off >= 1; off >>= 1) {
        s0 += __shfl_xor(s0, off); s1 += __shfl_xor(s1, off);
        s2 += __shfl_xor(s2, off); s3 += __shfl_xor(s3, off);
        s4 += __shfl_xor(s4, off); s5 += __shfl_xor(s5, off);
        s6 += __shfl_xor(s6, off); s7 += __shfl_xor(s7, off);
    }
    float l0=s0+bg[0], l1=s1+bg[1], l2=s2+bg[2], l3=s3+bg[3];
    float l4=s4+bg[4], l5=s5+bg[5], l6=s6+bg[6], l7=s7+bg[7];
    float m = fmaxf(fmaxf(fmaxf(l0,l1),fmaxf(l2,l3)), fmaxf(fmaxf(l4,l5),fmaxf(l6,l7)));
    float e0=expf(l0-m), e1=expf(l1-m), e2=expf(l2-m), e3=expf(l3-m);
    float e4=expf(l4-m), e5=expf(l5-m), e6=expf(l6-m), e7=expf(l7-m);
    float inv = 1.f / (e0+e1+e2+e3+e4+e5+e6+e7);
    if (lane == 0) {
        float* wo = wout + t * NH;
        wo[0]=e0*inv; wo[1]=e1*inv; wo[2]=e2*inv; wo[3]=e3*inv;
        wo[4]=e4*inv; wo[5]=e5*inv; wo[6]=e6*inv; wo[7]=e7*inv;
    }
}

// ============ 256xTN x64 bf16 GEMM — 16 waves (4/SIMD), occupancy-driven overlap ============
// R15/R17 core (measured best: 1368 us total) — K-loop FROZEN. NEW: TN template param
// (N-tile 256 or 128). TN=128 exists solely so gemm0 (N=1024) fills all 256 CUs
// (grid 32x8=256 vs 128 at TN=256). Wave out 64 x TN/4; acc[4][TN/64]; B LDS 2 x TN*128B.
// Swizzle invariant: all fragment rows have row&7 == lane&7 -> conflict-free at any TN.
// 16 waves as 4M x 4N; __launch_bounds__(1024,4) -> VGPR<=128, 4 waves/SIMD resident
// (m114 implicit LDS/MFMA overlap). LDS: A 3x32K + B 2x(TN*128)B. Stages at tile top
// (B(t+1), A(t+2)); boundary vmcnt(2) keeps A(t+2) in flight; one barrier/tile.
// MAP 1 (gemm1): per round of 256 ids, XCD x (=id&7) works a contiguous 4bx x 8by rectangle.
// MAP 2 (gemm2): bz = id&7 -> one K-chunk per XCD; bx,by sweep within.
// EPI 0: gelu(acc+bias[col]+sp[t>>11][col])        -> bf16 outH (unswizzled)
// EPI 1: w[t][col>>12]*gelu(acc+bias[col])         -> bf16 outH (swizzled)
// EPI 2: bz==0: acc+sum_h w*b2 -> outF (f32) ; bz>0: acc -> parts[bz-1] (bf16, safe per R14)
template<int EPI, int MAP, int TN>
__global__ __launch_bounds__(1024, 4) void k_g2(
    const bf16* __restrict__ A, long lda,
    const bf16* __restrict__ Bt, long ldb,
    int K, long kcs, int gm, int gn,
    bf16* __restrict__ outH, float* __restrict__ outF, long ldc,
    const float* __restrict__ bias,
    const float* __restrict__ aux1, const float* __restrict__ aux2,
    bf16* __restrict__ parts, long pStride)
{
    constexpr int NF = TN / 64;                 // B fragments per wave (4 or 2)
    constexpr int WN = TN / 4;                  // wave N extent (64 or 32)
    __shared__ __align__(16) unsigned char lsA[3][32 * 1024];
    __shared__ __align__(16) unsigned char lsB[2][TN * 128];
    const int tid = threadIdx.x, lane = tid & 63, wid = tid >> 6;

    const int id = blockIdx.x;
    int bx, by, bz;
    if (MAP == 1) {            // grid 1024 = 8bx x 128by, rounds of 256
        const int x = id & 7, j = (id >> 3) & 31, r = id >> 8;
        bx = (x & 1) * 4 + (j & 3);
        by = (x >> 1) * 8 + (j >> 2) + r * 32;
        bz = 0;
    } else if (MAP == 2) {     // grid 256 = 8bx x 4by x 8bz
        bz = id & 7;
        bx = (id >> 3) & 7;
        by = id >> 6;
    } else {
        bx = id % gm; by = (id / gm) % gn; bz = id / (gm * gn);
    }
    const long tileM = (long)bx * 256;
    const long tileN = (long)by * TN;
    const bf16* Ab = A + tileM * lda + (long)bz * kcs;
    const bf16* Bb = Bt + tileN * ldb + (long)bz * kcs;

    const int wr = wid >> 2, wc = wid & 3;      // 4 x 4 waves, wave out 64 x WN
    const int l15 = lane & 15, kd = lane >> 4;
    const int swz = (lane & 7) << 4;

    f32x4 acc[4][NF];
    #pragma unroll
    for (int m = 0; m < 4; ++m)
        #pragma unroll
        for (int n = 0; n < NF; ++n) { f32x4 z = {0.f,0.f,0.f,0.f}; acc[m][n] = z; }

    auto STAGE_A = [&](int t) {
        const int buf = t % 3; const long kO = (long)t * 64;
        #pragma unroll
        for (int is = 0; is < 2; ++is) {
            const int o = is * 16384 + tid * 16;
            gload16(Ab + (long)(o >> 7) * lda + kO + ((o & 127) >> 1), lsA[buf] + o);
        }
    };
    auto STAGE_B = [&](int t) {
        const int buf = t & 1; const long kO = (long)t * 64;
        #pragma unroll
        for (int is = 0; is < TN / 128; ++is) {
            const int o = is * 16384 + tid * 16;
            gload16(Bb + (long)(o >> 7) * ldb + kO + ((o & 127) >> 1), lsB[buf] + o);
        }
    };

    const int NT = K >> 6;                      // >= 16 at all call sites
    STAGE_A(0); STAGE_B(0); STAGE_A(1);
    asm volatile("s_waitcnt vmcnt(2)" ::: "memory");
    __builtin_amdgcn_s_barrier();
    for (int t = 0; t < NT; ++t) {
        const unsigned char* As = lsA[t % 3];
        const unsigned char* Bs = lsB[t & 1];
        if (t + 1 < NT) STAGE_B(t + 1);
        if (t + 2 < NT) STAGE_A(t + 2);
        #pragma unroll
        for (int kk = 0; kk < 2; ++kk) {
            const int kb = (kk * 64 + kd * 16) ^ swz;
            bf16x8 av[4], bv[NF];
            #pragma unroll
            for (int m = 0; m < 4; ++m)
                av[m] = *(const bf16x8*)(As + ((wr * 64 + m * 16 + l15) << 7) + kb);
            #pragma unroll
            for (int n = 0; n < NF; ++n)
                bv[n] = *(const bf16x8*)(Bs + ((wc * WN + n * 16 + l15) << 7) + kb);
            __builtin_amdgcn_s_setprio(1);
            #pragma unroll
            for (int m = 0; m < 4; ++m)
                #pragma unroll
                for (int n = 0; n < NF; ++n)
                    acc[m][n] = __builtin_amdgcn_mfma_f32_16x16x32_bf16(av[m], bv[n], acc[m][n], 0, 0, 0);
            __builtin_amdgcn_s_setprio(0);
        }
        if (t + 2 < NT) {
            asm volatile("s_waitcnt vmcnt(2)" ::: "memory");
        } else {
            asm volatile("s_waitcnt vmcnt(0)" ::: "memory");
        }
        __builtin_amdgcn_s_barrier();
    }

    // epilogue: C/D layout col = lane&15, row = (lane>>4)*4 + j
    const long rowBase = tileM + wr * 64;
    const int  colBase = (int)tileN + wc * WN;
    #pragma unroll
    for (int m = 0; m < 4; ++m) {
        const long r0 = rowBase + m * 16 + (kd * 4);
        #pragma unroll
        for (int n = 0; n < NF; ++n) {
            const int col = colBase + n * 16 + l15;
            #pragma unroll
            for (int j = 0; j < 4; ++j) {
                const long tk = r0 + j;
                float v = acc[m][n][j];
                if constexpr (EPI == 0) {
                    v += bias[col] + aux1[(long)(tk >> 11) * DM + col];
                    v = gelu_f(v);
                    outH[tk * ldc + col] = (bf16)v;
                } else if constexpr (EPI == 1) {
                    v += bias[col];
                    v = gelu_f(v);
                    v *= aux1[tk * NH + (col >> 12)];
                    outH[tk * ldc + (col ^ (((int)tk & 7) << 3))] = (bf16)v;
                } else {
                    if (bz == 0) {
                        float bsum = 0.f;
                        #pragma unroll
                        for (int hh = 0; hh < NH; ++hh)
                            bsum += aux1[tk * NH + hh] * aux2[(long)hh * DM + col];
                        outF[tk * ldc + col] = v + bsum;
                    } else {
                        parts[(long)(bz - 1) * pStride + tk * ldc + col] = (bf16)v;
                    }
                }
            }
        }
    }
}

// ---------------- reduce: out += sum of bf16 partials (8 elems/thread) ----------------
__global__ __launch_bounds__(256) void k_red(float* __restrict__ out, const bf16* __restrict__ parts,
                                             long pStride) {
    long i = ((long)blockIdx.x * 256 + threadIdx.x) * 8;
    float4 v0 = *(float4*)(out + i);
    float4 v1 = *(float4*)(out + i + 4);
    #pragma unroll
    for (int p = 0; p < NKS - 1; ++p) {
        bf16x8 q = *(const bf16x8*)(parts + (long)p * pStride + i);
        v0.x += (float)q[0]; v0.y += (float)q[1]; v0.z += (float)q[2]; v0.w += (float)q[3];
        v1.x += (float)q[4]; v1.y += (float)q[5]; v1.z += (float)q[6]; v1.w += (float)q[7];
    }
    *(float4*)(out + i) = v0;
    *(float4*)(out + i + 4) = v1;
}

extern "C" void kernel_launch(void* const* d_in, const int* in_sizes, int n_in,
                              void* d_out, int out_size, void* d_ws, size_t ws_size,
                              hipStream_t stream)
{
    const float* x  = (const float*)d_in[0];
    const float* rs = (const float*)d_in[1];
    const float* W1 = (const float*)d_in[2];
    const float* b1 = (const float*)d_in[3];
    const float* W2 = (const float*)d_in[4];
    const float* b2 = (const float*)d_in[5];
    const float* Ws = (const float*)d_in[6];
    const float* bs = (const float*)d_in[7];
    const float* Wi = (const float*)d_in[8];
    const float* bi = (const float*)d_in[9];
    const float* Wg = (const float*)d_in[10];
    const float* bg = (const float*)d_in[11];

    float* out  = (float*)d_out;                    // [8192][1024] f32
    float* wout = out + (size_t)MT * DM;            // [8192][8]   f32 (output 1)

    unsigned char* ws = (unsigned char*)d_ws;
    size_t ofs = 0;
    auto alloc = [&](size_t bytes) { void* p = ws + ofs; ofs += (bytes + 255) & ~(size_t)255; return p; };

    bf16*  xbf  = (bf16*)alloc((size_t)MT * DM * 2);          // 16.8 MB (swizzled)
    bf16*  WiT  = (bf16*)alloc((size_t)DM * DM * 2);          //  2.1 MB (swizzled)
    bf16*  g    = (bf16*)alloc((size_t)MT * DM * 2);          // 16.8 MB (linear)
    float* sp   = (float*)alloc((size_t)NB * DM * 4);         // 16 KB
    bf16*  W1T  = (bf16*)alloc((size_t)NH * DF * DM * 2);     // 67.1 MB [hf][d] swizzled
    bf16*  W2T  = (bf16*)alloc((size_t)NH * DF * DM * 2);     // 67.1 MB [d][hf] swizzled
    bf16*  hp   = (bf16*)alloc((size_t)MQ * NH * DF * 2);     // 134.2 MB (swizzled, L3-resident)
    bf16*  part = (bf16*)alloc((size_t)(NKS - 1) * MQ * DM * 2);   // 29.4 MB (bf16)
    const long pStride = (long)MQ * DM;

    // stage 0: conversions / transposes / projections
    k_cvtx<<<(MT * DM) / (256 * 8), 256, 0, stream>>>(x, xbf);
    k_tcvt2<<<dim3(DM / 64, DM / 64, 1), 256, 0, stream>>>(Wi, WiT, DM, DM, 0, 0);
    k_sproj2<<<dim3(DM / 16, NB), 256, 0, stream>>>(rs, Ws, bs, sp);

    // stage 1: input proj (TN=128 -> grid 256, full machine) -> g, then gate weights
    k_g2<0, 0, 128><<<(MT / 256) * (DM / 128), 1024, 0, stream>>>(
        xbf, DM, WiT, DM, DM, 0, MT / 256, DM / 128,
        g, nullptr, DM, bi, sp, nullptr, nullptr, 0);
    k_gate<<<MT / 4, 256, 0, stream>>>(g, Wg, bg, wout);

    // weight transposes
    k_tcvt2<<<dim3(DF / 64, DM / 64, NH), 256, 0, stream>>>(
        W1, W1T, DF, DM, (long)DM * DF, (long)DF * DM);
    k_tcvt2<<<dim3(DM / 64, DF / 64, NH), 256, 0, stream>>>(
        W2, W2T, DM, (long)NH * DF, (long)DF * DM, DF);

    // stage 2: per M-quarter: gemm1 (all heads) -> hp ; gemm2 (K-split 8) ; reduce
    for (int q = 0; q < MT / MQ; ++q) {
        const bf16*  xq = xbf + (size_t)q * MQ * DM;
        const float* wq = wout + (size_t)q * MQ * NH;
        float*       oq = out + (size_t)q * MQ * DM;
        k_g2<1, 1, 256><<<(MQ / 256) * (NH * DF / 256), 1024, 0, stream>>>(
            xq, DM, W1T, DM, DM, 0, MQ / 256, NH * DF / 256,
            hp, nullptr, (long)NH * DF, b1, wq, nullptr, nullptr, 0);
        k_g2<2, 2, 256><<<(MQ / 256) * (DM / 256) * NKS, 1024, 0, stream>>>(
            hp, (long)NH * DF, W2T, (long)NH * DF, KC, KC, MQ / 256, DM / 256,
            nullptr, oq, DM, nullptr, wq, b2, part, pStride);
        k_red<<<(MQ * DM) / (256 * 8), 256, 0, stream>>>(oq, part, pStride);
    }
    (void)in_sizes; (void)n_in; (void)out_size;
}